// Round 7
// baseline (390.352 us; speedup 1.0000x reference)
//
#include <hip/hip_runtime.h>

#define D 32
#define K_CODES 8192
#define N_ROWS 16384
#define TPB 256
#define ROWS_PER_T 2
#define ROWS_PB (TPB * ROWS_PER_T)       // 512 rows per block
#define ROW_GROUPS (N_ROWS / ROWS_PB)    // 32
#define SPLITS 32
#define KPB (K_CODES / SPLITS)           // 256 codes per block

// ws layout (bytes)
#define WS_ROWBEST 0                      // u64 x 16384 = 131072
#define WS_USED    131072                 // u32 x 8192  = 32768
#define WS_MSE     163840                 // f32 x 1
#define WS_MIND    163844                 // u32 x 8192  = 32768
#define WS_NHC     196612                 // f32 x 8192  = 32768

// Map float -> unsigned such that unsigned order == float order.
__device__ __forceinline__ unsigned sortkey(float f) {
    unsigned b = __float_as_uint(f);
    return b ^ ((unsigned)((int)b >> 31) | 0x80000000u);
}

// One DPP min step: v = min(v, dpp_move(v)). bound_ctrl=false + row_mask keeps
// non-receiving lanes at old value (harmless self-min).
template <int CTRL, int RMASK>
__device__ __forceinline__ float dppmin(float v) {
    int m = __builtin_amdgcn_update_dpp(__float_as_int(v), __float_as_int(v),
                                        CTRL, RMASK, 0xF, false);
    return fminf(v, __int_as_float(m));
}

// Pass 0: negHalfC[k] = -0.5 * ||c_k||^2
__global__ __launch_bounds__(TPB) void vq_nhc(const float* __restrict__ cb,
                                              float* __restrict__ nhc) {
    const int k = blockIdx.x * TPB + threadIdx.x;
    const float4* p = (const float4*)cb + (size_t)k * 8;
    float s = 0.f;
    #pragma unroll
    for (int w = 0; w < 8; ++w) {
        float4 v = p[w];
        s += v.x * v.x + v.y * v.y + v.z * v.z + v.w * v.w;
    }
    nhc[k] = -0.5f * s;
}

// Per-code body: dot both rows, update scalar argmax, DPP-min across wave,
// one atomicMin per wave per code. All indices static.
#define VQ_CODE_STEP(CV, TT, KK)                                          \
    {                                                                     \
        float t0 = (TT), t1 = (TT);                                       \
        _Pragma("unroll")                                                 \
        for (int w = 0; w < 8; ++w) {                                     \
            const float4 cv = (CV)[w];                                    \
            t0 += cv.x * x0[w].x; t0 += cv.y * x0[w].y;                   \
            t0 += cv.z * x0[w].z; t0 += cv.w * x0[w].w;                   \
            t1 += cv.x * x1[w].x; t1 += cv.y * x1[w].y;                   \
            t1 += cv.z * x1[w].z; t1 += cv.w * x1[w].w;                   \
        }                                                                 \
        const int kg = kbase + (KK);                                      \
        if (t0 > bs0) { bs0 = t0; bi0 = kg; }                             \
        if (t1 > bs1) { bs1 = t1; bi1 = kg; }                             \
        float m = fminf(__builtin_fmaf(-2.f, t0, xx0),                    \
                        __builtin_fmaf(-2.f, t1, xx1));                   \
        m = dppmin<0xB1,  0xF>(m);  /* quad_perm xor1 */                  \
        m = dppmin<0x4E,  0xF>(m);  /* quad_perm xor2 */                  \
        m = dppmin<0x141, 0xF>(m);  /* row_half_mirror */                 \
        m = dppmin<0x140, 0xF>(m);  /* row_mirror */                      \
        m = dppmin<0x142, 0xA>(m);  /* row_bcast15 -> rows 1,3 */         \
        m = dppmin<0x143, 0xC>(m);  /* row_bcast31 -> rows 2,3 */         \
        if ((tid & 63) == 63) atomicMin(&minD[kg], __float_as_uint(m));   \
    }

// Pass 1: rows in registers (2/thread, scalar argmax state), codes streamed
// as wave-uniform global loads with explicit ping-pong prefetch.
__global__ __launch_bounds__(TPB, 3) void vq_dist(
    const float* __restrict__ x, const float* __restrict__ cb,
    const float* __restrict__ nhc,
    unsigned long long* __restrict__ rowBest, unsigned* __restrict__ minD)
{
    const int tid = threadIdx.x;
    const int rg  = blockIdx.x & (ROW_GROUPS - 1);
    const int sp  = blockIdx.x >> 5;              // / ROW_GROUPS
    const int r0  = rg * ROWS_PB + tid;
    const int r1  = r0 + TPB;
    const int kbase = sp * KPB;

    // Own rows -> registers (coalesced float4 loads).
    float4 x0[8], x1[8];
    {
        const float4* xp0 = (const float4*)x + (size_t)r0 * 8;
        const float4* xp1 = (const float4*)x + (size_t)r1 * 8;
        #pragma unroll
        for (int w = 0; w < 8; ++w) { x0[w] = xp0[w]; x1[w] = xp1[w]; }
    }
    float xx0 = 0.f, xx1 = 0.f;
    #pragma unroll
    for (int w = 0; w < 8; ++w) {
        xx0 += x0[w].x*x0[w].x + x0[w].y*x0[w].y + x0[w].z*x0[w].z + x0[w].w*x0[w].w;
        xx1 += x1[w].x*x1[w].x + x1[w].y*x1[w].y + x1[w].z*x1[w].z + x1[w].w*x1[w].w;
    }

    float bs0 = -3.0e38f, bs1 = -3.0e38f;
    int   bi0 = 0,        bi1 = 0;

    const float4* cbp  = (const float4*)cb + (size_t)kbase * 8;
    const float*  nhcp = nhc + kbase;

    // Ping-pong code buffers: compute one code while the other loads.
    float4 cva[8], cvb[8];
    float  ta, tb;
    #pragma unroll
    for (int w = 0; w < 8; ++w) cva[w] = cbp[w];
    ta = nhcp[0];

    for (int kk = 0; kk < KPB; kk += 2) {
        // prefetch code kk+1 into cvb
        #pragma unroll
        for (int w = 0; w < 8; ++w) cvb[w] = cbp[(size_t)(kk + 1) * 8 + w];
        tb = nhcp[kk + 1];
        VQ_CODE_STEP(cva, ta, kk);
        // prefetch code kk+2 into cva (wraps to 0 on last iter; dead but cheap)
        const int k2 = (kk + 2) & (KPB - 1);
        #pragma unroll
        for (int w = 0; w < 8; ++w) cva[w] = cbp[(size_t)k2 * 8 + w];
        ta = nhcp[k2];
        VQ_CODE_STEP(cvb, tb, kk + 1);
    }

    // Publish per-row best across code-splits: packed (sortkey(t)<<32)|~k.
    unsigned long long p0 = ((unsigned long long)sortkey(bs0) << 32) | (unsigned)(~bi0);
    unsigned long long p1 = ((unsigned long long)sortkey(bs1) << 32) | (unsigned)(~bi1);
    atomicMax(&rowBest[r0], p0);
    atomicMax(&rowBest[r1], p1);
}

// Pass 2: finalize tokens -> gather emb, write out, fused MSE, mark used.
__global__ __launch_bounds__(TPB) void vq_emit(
    const float* __restrict__ x, const float* __restrict__ cb,
    const unsigned long long* __restrict__ rowBest,
    unsigned* __restrict__ used, float* __restrict__ mse,
    float* __restrict__ out)
{
    const int r = blockIdx.x * TPB + threadIdx.x;
    const unsigned tok = ~(unsigned)(rowBest[r] & 0xFFFFFFFFull);
    used[tok] = 1u;                        // benign race: all writers store 1
    const float4* e4 = (const float4*)cb + (size_t)tok * 8;
    const float4* x4 = (const float4*)x + (size_t)r * 8;
    float4* o4 = (float4*)out + (size_t)r * 8;
    float part = 0.f;
    #pragma unroll
    for (int w = 0; w < 8; ++w) {
        float4 e = e4[w], xv = x4[w];
        o4[w] = e;
        float a = e.x - xv.x; part += a * a;
        a = e.y - xv.y; part += a * a;
        a = e.z - xv.z; part += a * a;
        a = e.w - xv.w; part += a * a;
    }
    #pragma unroll
    for (int off = 32; off > 0; off >>= 1) part += __shfl_xor(part, off, 64);
    if ((threadIdx.x & 63) == 0) atomicAdd(mse, part);
}

// Pass 3: entropy over unused codes + total loss scalar.
__global__ __launch_bounds__(TPB) void vq_finish(
    const unsigned* __restrict__ minD, const unsigned* __restrict__ used,
    const float* __restrict__ mse, float* __restrict__ out, int n_elems)
{
    __shared__ float pp[4];
    const int tid = threadIdx.x;
    float s = 0.f;
    for (int k = tid; k < K_CODES; k += TPB)
        if (used[k] == 0u) s += __uint_as_float(minD[k]);
    #pragma unroll
    for (int off = 32; off > 0; off >>= 1) s += __shfl_xor(s, off, 64);
    const int lane = tid & 63, wid = tid >> 6;
    if (lane == 0) pp[wid] = s;
    __syncthreads();
    if (tid == 0) {
        float ent = (pp[0] + pp[1] + pp[2] + pp[3]) / (float)K_CODES;
        float m = mse[0] / (float)n_elems;
        out[n_elems] = 1.25f * m + 0.1f * ent;   // embedding+commitment+entropy
    }
}

extern "C" void kernel_launch(void* const* d_in, const int* in_sizes, int n_in,
                              void* d_out, int out_size, void* d_ws, size_t ws_size,
                              hipStream_t stream)
{
    (void)n_in; (void)out_size; (void)ws_size;
    const float* x  = (const float*)d_in[0];
    const float* cb = (const float*)d_in[1];
    float* out = (float*)d_out;
    const int n_elems = in_sizes[0];                 // 524288

    char* ws = (char*)d_ws;
    unsigned long long* rowBest = (unsigned long long*)(ws + WS_ROWBEST);
    unsigned* used = (unsigned*)(ws + WS_USED);
    float*    mse  = (float*)   (ws + WS_MSE);
    unsigned* minD = (unsigned*)(ws + WS_MIND);
    float*    nhc  = (float*)   (ws + WS_NHC);

    // rowBest(0) + used(0) + mse(0) in one memset; minD to +inf-proxy.
    hipMemsetAsync(ws, 0, WS_MSE + 4, stream);
    hipMemsetAsync(ws + WS_MIND, 0x7F, K_CODES * 4, stream);   // 3.39e38

    vq_nhc <<<K_CODES / TPB, TPB, 0, stream>>>(cb, nhc);
    vq_dist<<<ROW_GROUPS * SPLITS, TPB, 0, stream>>>(x, cb, nhc, rowBest, minD);
    vq_emit<<<N_ROWS / TPB, TPB, 0, stream>>>(x, cb, rowBest, used, mse, out);
    vq_finish<<<1, TPB, 0, stream>>>(minD, used, mse, out, n_elems);
}

// Round 8
// 387.089 us; speedup vs baseline: 1.0084x; 1.0084x over previous
//
#include <hip/hip_runtime.h>

#define D 32
#define K_CODES 8192
#define N_ROWS 16384
#define TPB 256
#define ROWS_PER_T 2
#define ROWS_PB (TPB * ROWS_PER_T)       // 512 rows per block
#define ROW_GROUPS (N_ROWS / ROWS_PB)    // 32
#define SPLITS 32
#define KPB (K_CODES / SPLITS)           // 256 codes per block

// ws layout (bytes)
#define WS_ROWBEST 0                      // u64 x 16384 = 131072
#define WS_USED    131072                 // u32 x 8192  = 32768
#define WS_MSE     163840                 // f32 x 1
#define WS_MIND    163844                 // u32 x 8192  = 32768
#define WS_NHC     196612                 // f32 x 8192  = 32768

// Map float -> unsigned such that unsigned order == float order.
__device__ __forceinline__ unsigned sortkey(float f) {
    unsigned b = __float_as_uint(f);
    return b ^ ((unsigned)((int)b >> 31) | 0x80000000u);
}

// One DPP min step: v = min(v, dpp_move(v)). bound_ctrl=false + row_mask keeps
// non-receiving lanes at old value (harmless self-min).
template <int CTRL, int RMASK>
__device__ __forceinline__ float dppmin(float v) {
    int m = __builtin_amdgcn_update_dpp(__float_as_int(v), __float_as_int(v),
                                        CTRL, RMASK, 0xF, false);
    return fminf(v, __int_as_float(m));
}

// Pass 0: negHalfC[k] = -0.5 * ||c_k||^2
__global__ __launch_bounds__(TPB) void vq_nhc(const float* __restrict__ cb,
                                              float* __restrict__ nhc) {
    const int k = blockIdx.x * TPB + threadIdx.x;
    const float4* p = (const float4*)cb + (size_t)k * 8;
    float s = 0.f;
    #pragma unroll
    for (int w = 0; w < 8; ++w) {
        float4 v = p[w];
        s += v.x * v.x + v.y * v.y + v.z * v.z + v.w * v.w;
    }
    nhc[k] = -0.5f * s;
}

// Per-code body: dot both rows, update scalar argmax, DPP-min across wave,
// one atomicMin per wave per code. All indices static.
#define VQ_CODE_STEP(CV, TT, KK)                                          \
    {                                                                     \
        float t0 = (TT), t1 = (TT);                                       \
        _Pragma("unroll")                                                 \
        for (int w = 0; w < 8; ++w) {                                     \
            const float4 cv = (CV)[w];                                    \
            t0 += cv.x * x0[w].x; t0 += cv.y * x0[w].y;                   \
            t0 += cv.z * x0[w].z; t0 += cv.w * x0[w].w;                   \
            t1 += cv.x * x1[w].x; t1 += cv.y * x1[w].y;                   \
            t1 += cv.z * x1[w].z; t1 += cv.w * x1[w].w;                   \
        }                                                                 \
        const int kg = kbase + (KK);                                      \
        if (t0 > bs0) { bs0 = t0; bi0 = kg; }                             \
        if (t1 > bs1) { bs1 = t1; bi1 = kg; }                             \
        float m = fminf(__builtin_fmaf(-2.f, t0, xx0),                    \
                        __builtin_fmaf(-2.f, t1, xx1));                   \
        m = dppmin<0xB1,  0xF>(m);  /* quad_perm xor1 */                  \
        m = dppmin<0x4E,  0xF>(m);  /* quad_perm xor2 */                  \
        m = dppmin<0x141, 0xF>(m);  /* row_half_mirror */                 \
        m = dppmin<0x140, 0xF>(m);  /* row_mirror */                      \
        m = dppmin<0x142, 0xA>(m);  /* row_bcast15 -> rows 1,3 */         \
        m = dppmin<0x143, 0xC>(m);  /* row_bcast31 -> rows 2,3 */         \
        if ((tid & 63) == 63) atomicMin(&minD[kg], __float_as_uint(m));   \
    }

// Pass 1: rows in registers (2/thread, scalar argmax state), codes streamed
// as wave-uniform global loads with explicit ping-pong prefetch.
// amdgpu_waves_per_eu(3,3): pin BOTH min and max waves/EU. launch_bounds'
// 2nd arg only raises the reg ceiling; the allocator still chases its
// default 8-10 waves/EU target and spills (r6: VGPR=48, r7: VGPR=64,
// 36 MB scratch writes). Pinning max=3 gives budget 512/3=170 >= ~150 live.
__global__ __launch_bounds__(TPB)
__attribute__((amdgpu_waves_per_eu(3, 3))) void vq_dist(
    const float* __restrict__ x, const float* __restrict__ cb,
    const float* __restrict__ nhc,
    unsigned long long* __restrict__ rowBest, unsigned* __restrict__ minD)
{
    const int tid = threadIdx.x;
    const int rg  = blockIdx.x & (ROW_GROUPS - 1);
    const int sp  = blockIdx.x >> 5;              // / ROW_GROUPS
    const int r0  = rg * ROWS_PB + tid;
    const int r1  = r0 + TPB;
    const int kbase = sp * KPB;

    // Own rows -> registers (coalesced float4 loads).
    float4 x0[8], x1[8];
    {
        const float4* xp0 = (const float4*)x + (size_t)r0 * 8;
        const float4* xp1 = (const float4*)x + (size_t)r1 * 8;
        #pragma unroll
        for (int w = 0; w < 8; ++w) { x0[w] = xp0[w]; x1[w] = xp1[w]; }
    }
    float xx0 = 0.f, xx1 = 0.f;
    #pragma unroll
    for (int w = 0; w < 8; ++w) {
        xx0 += x0[w].x*x0[w].x + x0[w].y*x0[w].y + x0[w].z*x0[w].z + x0[w].w*x0[w].w;
        xx1 += x1[w].x*x1[w].x + x1[w].y*x1[w].y + x1[w].z*x1[w].z + x1[w].w*x1[w].w;
    }

    float bs0 = -3.0e38f, bs1 = -3.0e38f;
    int   bi0 = 0,        bi1 = 0;

    const float4* cbp  = (const float4*)cb + (size_t)kbase * 8;
    const float*  nhcp = nhc + kbase;

    // Ping-pong code buffers: compute one code while the other loads.
    float4 cva[8], cvb[8];
    float  ta, tb;
    #pragma unroll
    for (int w = 0; w < 8; ++w) cva[w] = cbp[w];
    ta = nhcp[0];

    for (int kk = 0; kk < KPB; kk += 2) {
        // prefetch code kk+1 into cvb
        #pragma unroll
        for (int w = 0; w < 8; ++w) cvb[w] = cbp[(size_t)(kk + 1) * 8 + w];
        tb = nhcp[kk + 1];
        VQ_CODE_STEP(cva, ta, kk);
        // prefetch code kk+2 into cva (wraps to 0 on last iter; dead but cheap)
        const int k2 = (kk + 2) & (KPB - 1);
        #pragma unroll
        for (int w = 0; w < 8; ++w) cva[w] = cbp[(size_t)k2 * 8 + w];
        ta = nhcp[k2];
        VQ_CODE_STEP(cvb, tb, kk + 1);
    }

    // Publish per-row best across code-splits: packed (sortkey(t)<<32)|~k.
    unsigned long long p0 = ((unsigned long long)sortkey(bs0) << 32) | (unsigned)(~bi0);
    unsigned long long p1 = ((unsigned long long)sortkey(bs1) << 32) | (unsigned)(~bi1);
    atomicMax(&rowBest[r0], p0);
    atomicMax(&rowBest[r1], p1);
}

// Pass 2: finalize tokens -> gather emb, write out, fused MSE, mark used.
__global__ __launch_bounds__(TPB) void vq_emit(
    const float* __restrict__ x, const float* __restrict__ cb,
    const unsigned long long* __restrict__ rowBest,
    unsigned* __restrict__ used, float* __restrict__ mse,
    float* __restrict__ out)
{
    const int r = blockIdx.x * TPB + threadIdx.x;
    const unsigned tok = ~(unsigned)(rowBest[r] & 0xFFFFFFFFull);
    used[tok] = 1u;                        // benign race: all writers store 1
    const float4* e4 = (const float4*)cb + (size_t)tok * 8;
    const float4* x4 = (const float4*)x + (size_t)r * 8;
    float4* o4 = (float4*)out + (size_t)r * 8;
    float part = 0.f;
    #pragma unroll
    for (int w = 0; w < 8; ++w) {
        float4 e = e4[w], xv = x4[w];
        o4[w] = e;
        float a = e.x - xv.x; part += a * a;
        a = e.y - xv.y; part += a * a;
        a = e.z - xv.z; part += a * a;
        a = e.w - xv.w; part += a * a;
    }
    #pragma unroll
    for (int off = 32; off > 0; off >>= 1) part += __shfl_xor(part, off, 64);
    if ((threadIdx.x & 63) == 0) atomicAdd(mse, part);
}

// Pass 3: entropy over unused codes + total loss scalar.
__global__ __launch_bounds__(TPB) void vq_finish(
    const unsigned* __restrict__ minD, const unsigned* __restrict__ used,
    const float* __restrict__ mse, float* __restrict__ out, int n_elems)
{
    __shared__ float pp[4];
    const int tid = threadIdx.x;
    float s = 0.f;
    for (int k = tid; k < K_CODES; k += TPB)
        if (used[k] == 0u) s += __uint_as_float(minD[k]);
    #pragma unroll
    for (int off = 32; off > 0; off >>= 1) s += __shfl_xor(s, off, 64);
    const int lane = tid & 63, wid = tid >> 6;
    if (lane == 0) pp[wid] = s;
    __syncthreads();
    if (tid == 0) {
        float ent = (pp[0] + pp[1] + pp[2] + pp[3]) / (float)K_CODES;
        float m = mse[0] / (float)n_elems;
        out[n_elems] = 1.25f * m + 0.1f * ent;   // embedding+commitment+entropy
    }
}

extern "C" void kernel_launch(void* const* d_in, const int* in_sizes, int n_in,
                              void* d_out, int out_size, void* d_ws, size_t ws_size,
                              hipStream_t stream)
{
    (void)n_in; (void)out_size; (void)ws_size;
    const float* x  = (const float*)d_in[0];
    const float* cb = (const float*)d_in[1];
    float* out = (float*)d_out;
    const int n_elems = in_sizes[0];                 // 524288

    char* ws = (char*)d_ws;
    unsigned long long* rowBest = (unsigned long long*)(ws + WS_ROWBEST);
    unsigned* used = (unsigned*)(ws + WS_USED);
    float*    mse  = (float*)   (ws + WS_MSE);
    unsigned* minD = (unsigned*)(ws + WS_MIND);
    float*    nhc  = (float*)   (ws + WS_NHC);

    // rowBest(0) + used(0) + mse(0) in one memset; minD to +inf-proxy.
    hipMemsetAsync(ws, 0, WS_MSE + 4, stream);
    hipMemsetAsync(ws + WS_MIND, 0x7F, K_CODES * 4, stream);   // 3.39e38

    vq_nhc <<<K_CODES / TPB, TPB, 0, stream>>>(cb, nhc);
    vq_dist<<<ROW_GROUPS * SPLITS, TPB, 0, stream>>>(x, cb, nhc, rowBest, minD);
    vq_emit<<<N_ROWS / TPB, TPB, 0, stream>>>(x, cb, rowBest, used, mse, out);
    vq_finish<<<1, TPB, 0, stream>>>(minD, used, mse, out, n_elems);
}

// Round 12
// 217.955 us; speedup vs baseline: 1.7910x; 1.7760x over previous
//
#include <hip/hip_runtime.h>

#define D 32
#define K_CODES 8192
#define N_ROWS 16384
#define TPB 256
#define SPLITS 4
#define CPW (K_CODES / SPLITS)     // 2048 codes per wave
#define TILES (CPW / 16)           // 128 code-tiles per wave

typedef __attribute__((ext_vector_type(8))) short short8;   // 8 bf16 = 4 VGPR
typedef __attribute__((ext_vector_type(4))) float f32x4;    // MFMA C/D

// ws layout (bytes)
#define WS_ROWBEST 0               // u64 x 16384 = 131072
#define WS_USED    131072          // u32 x 8192
#define WS_MIND    163840          // u32 x 8192
#define WS_MSE     196608          // f32 (+pad)
#define WS_XX      196864          // f32 x 16384
#define WS_NHC     262400          // f32 x 8192
#define WS_XHI     295168          // bf16 x 16384*32 = 1 MB
#define WS_XLO     1343744         // 1 MB
#define WS_CHI     2392320         // bf16 x 8192*32 = 512 KB
#define WS_CLO     2916608         // 512 KB -> total 3440896 B

__device__ __forceinline__ unsigned sortkey(float f) {
    unsigned b = __float_as_uint(f);
    return b ^ ((unsigned)((int)b >> 31) | 0x80000000u);
}
// round-to-nearest-even fp32 -> bf16 (as ushort)
__device__ __forceinline__ unsigned rnbf16(float f) {
    unsigned u = __float_as_uint(f);
    return (u + 0x7FFFu + ((u >> 16) & 1u)) >> 16;
}
__device__ __forceinline__ float frombf16(unsigned h) {
    return __uint_as_float(h << 16);
}

// Pass 0: split rows+codes into hi/lo bf16; exact fp32 norms.
__global__ __launch_bounds__(TPB) void vq_prep(
    const float* __restrict__ x, const float* __restrict__ cb,
    ushort* __restrict__ xhi, ushort* __restrict__ xlo,
    ushort* __restrict__ chi, ushort* __restrict__ clo,
    float* __restrict__ xx, float* __restrict__ nhc)
{
    const int id = blockIdx.x * TPB + threadIdx.x;      // 0..24575
    const bool isrow = id < N_ROWS;
    const int e = isrow ? id : id - N_ROWS;
    const float4* src = (const float4*)(isrow ? x + (size_t)e * D
                                              : cb + (size_t)e * D);
    uint2* dhi = (uint2*)((isrow ? xhi : chi) + (size_t)e * D);
    uint2* dlo = (uint2*)((isrow ? xlo : clo) + (size_t)e * D);
    float ss = 0.f;
    #pragma unroll
    for (int w = 0; w < 8; ++w) {
        float4 v = src[w];
        ss += v.x*v.x + v.y*v.y + v.z*v.z + v.w*v.w;
        unsigned h0 = rnbf16(v.x), h1 = rnbf16(v.y);
        unsigned h2 = rnbf16(v.z), h3 = rnbf16(v.w);
        unsigned l0 = rnbf16(v.x - frombf16(h0)), l1 = rnbf16(v.y - frombf16(h1));
        unsigned l2 = rnbf16(v.z - frombf16(h2)), l3 = rnbf16(v.w - frombf16(h3));
        uint2 ph; ph.x = h0 | (h1 << 16); ph.y = h2 | (h3 << 16);
        uint2 pl; pl.x = l0 | (l1 << 16); pl.y = l2 | (l3 << 16);
        dhi[w] = ph; dlo[w] = pl;
    }
    if (isrow) xx[e] = ss; else nhc[e] = -0.5f * ss;
}

// score-slot update: s = acc[j]; track per-(row-slot,class) best + tile min-dist
#define UPD(ACC, J, BS, BK, XXV)                                    \
    { float s_ = (ACC)[J];                                          \
      if (s_ > (BS)) { (BS) = s_; (BK) = kk; }                      \
      md = fminf(md, __builtin_fmaf(-2.f, s_, (XXV))); }

// class-reduce packed best across the 16 cls lanes, publish one atomic
#define FLUSH(BS, BK, ROW)                                               \
    { unsigned kg = (unsigned)(kbase + (BK) * 16 + cls);                 \
      unsigned long long pk =                                            \
          ((unsigned long long)sortkey(BS) << 32) | (unsigned)(~kg);     \
      unsigned long long o_;                                             \
      o_ = __shfl_xor(pk, 1, 64); if (o_ > pk) pk = o_;                  \
      o_ = __shfl_xor(pk, 2, 64); if (o_ > pk) pk = o_;                  \
      o_ = __shfl_xor(pk, 4, 64); if (o_ > pk) pk = o_;                  \
      o_ = __shfl_xor(pk, 8, 64); if (o_ > pk) pk = o_;                  \
      if (cls == 0) atomicMax(&rowBest[ROW], pk); }

// Pass 1: split-bf16 MFMA distance sweep.
// Wave = 32 rows (2 M-tiles) x 2048 codes. 4-term split (hh+lh+hl+ll) per
// 16x16x32 tile -> fp32-accurate scores. A/B use the SAME lane->k pattern
// from row-major [entity][dim] bf16, so any k-permutation mismatch cancels.
// C/D layout (HW-verified): col = lane&15 (code), row = (lane>>4)*4 + reg.
__global__ __launch_bounds__(TPB) void vq_dist(
    const ushort* __restrict__ xhi, const ushort* __restrict__ xlo,
    const ushort* __restrict__ chi, const ushort* __restrict__ clo,
    const float* __restrict__ xx, const float* __restrict__ nhc,
    unsigned long long* __restrict__ rowBest, unsigned* __restrict__ minD)
{
    const int tid  = threadIdx.x;
    const int lane = tid & 63;
    const int wid  = tid >> 6;            // 0..3 = code split
    const int r0   = blockIdx.x * 32;     // block = 32-row group, 4 waves share A
    const int kbase = wid * CPW;
    const int cls  = lane & 15;           // A: row-in-tile / B: code-in-tile
    const int ks   = (lane >> 4) * 8;     // k-slot base (assumed; cancels)
    const int rs   = (lane >> 4) * 4;     // C/D row-slot base

    // A fragments: constant over the whole sweep (16 VGPR pinned).
    const short8 ah0 = *(const short8*)(xhi + (size_t)(r0 + cls) * D + ks);
    const short8 al0 = *(const short8*)(xlo + (size_t)(r0 + cls) * D + ks);
    const short8 ah1 = *(const short8*)(xhi + (size_t)(r0 + 16 + cls) * D + ks);
    const short8 al1 = *(const short8*)(xlo + (size_t)(r0 + 16 + cls) * D + ks);

    // Row norms for my 8 C/D slots.
    const float xx00 = xx[r0 + rs + 0], xx01 = xx[r0 + rs + 1];
    const float xx02 = xx[r0 + rs + 2], xx03 = xx[r0 + rs + 3];
    const float xx10 = xx[r0 + 16 + rs + 0], xx11 = xx[r0 + 16 + rs + 1];
    const float xx12 = xx[r0 + 16 + rs + 2], xx13 = xx[r0 + 16 + rs + 3];

    float bs00 = -3.0e38f, bs01 = -3.0e38f, bs02 = -3.0e38f, bs03 = -3.0e38f;
    float bs10 = -3.0e38f, bs11 = -3.0e38f, bs12 = -3.0e38f, bs13 = -3.0e38f;
    int bk00 = 0, bk01 = 0, bk02 = 0, bk03 = 0;
    int bk10 = 0, bk11 = 0, bk12 = 0, bk13 = 0;

    const ushort* bhp = chi + ((size_t)(kbase + cls) * D + ks);
    const ushort* blp = clo + ((size_t)(kbase + cls) * D + ks);
    const float*  nvp = nhc + kbase + cls;

    for (int kk = 0; kk < TILES; ++kk) {
        const short8 bh = *(const short8*)bhp;
        const short8 bl = *(const short8*)blp;
        const float  nv = *nvp;
        bhp += 16 * D; blp += 16 * D; nvp += 16;

        f32x4 acc0 = {nv, nv, nv, nv};    // scores pre-biased with -||c||^2/2
        f32x4 acc1 = acc0;
        acc0 = __builtin_amdgcn_mfma_f32_16x16x32_bf16(ah0, bh, acc0, 0, 0, 0);
        acc1 = __builtin_amdgcn_mfma_f32_16x16x32_bf16(ah1, bh, acc1, 0, 0, 0);
        acc0 = __builtin_amdgcn_mfma_f32_16x16x32_bf16(al0, bh, acc0, 0, 0, 0);
        acc1 = __builtin_amdgcn_mfma_f32_16x16x32_bf16(al1, bh, acc1, 0, 0, 0);
        acc0 = __builtin_amdgcn_mfma_f32_16x16x32_bf16(ah0, bl, acc0, 0, 0, 0);
        acc1 = __builtin_amdgcn_mfma_f32_16x16x32_bf16(ah1, bl, acc1, 0, 0, 0);
        acc0 = __builtin_amdgcn_mfma_f32_16x16x32_bf16(al0, bl, acc0, 0, 0, 0);
        acc1 = __builtin_amdgcn_mfma_f32_16x16x32_bf16(al1, bl, acc1, 0, 0, 0);

        float md = 3.0e38f;               // min dist over 32 rows, my class col
        UPD(acc0, 0, bs00, bk00, xx00) UPD(acc0, 1, bs01, bk01, xx01)
        UPD(acc0, 2, bs02, bk02, xx02) UPD(acc0, 3, bs03, bk03, xx03)
        UPD(acc1, 0, bs10, bk10, xx10) UPD(acc1, 1, bs11, bk11, xx11)
        UPD(acc1, 2, bs12, bk12, xx12) UPD(acc1, 3, bs13, bk13, xx13)
        // fold the 4 row-groups holding this class column
        md = fminf(md, __shfl_xor(md, 16, 64));
        md = fminf(md, __shfl_xor(md, 32, 64));
        if (lane < 16)
            atomicMin(&minD[kbase + kk * 16 + cls], __float_as_uint(md));
    }

    FLUSH(bs00, bk00, r0 + rs + 0) FLUSH(bs01, bk01, r0 + rs + 1)
    FLUSH(bs02, bk02, r0 + rs + 2) FLUSH(bs03, bk03, r0 + rs + 3)
    FLUSH(bs10, bk10, r0 + 16 + rs + 0) FLUSH(bs11, bk11, r0 + 16 + rs + 1)
    FLUSH(bs12, bk12, r0 + 16 + rs + 2) FLUSH(bs13, bk13, r0 + 16 + rs + 3)
}

// Pass 2: finalize tokens -> gather emb, write out, fused MSE, mark used.
__global__ __launch_bounds__(TPB) void vq_emit(
    const float* __restrict__ x, const float* __restrict__ cb,
    const unsigned long long* __restrict__ rowBest,
    unsigned* __restrict__ used, float* __restrict__ mse,
    float* __restrict__ out)
{
    const int r = blockIdx.x * TPB + threadIdx.x;
    const unsigned tok = ~(unsigned)(rowBest[r] & 0xFFFFFFFFull);
    used[tok] = 1u;                        // benign race: all writers store 1
    const float4* e4 = (const float4*)cb + (size_t)tok * 8;
    const float4* x4 = (const float4*)x + (size_t)r * 8;
    float4* o4 = (float4*)out + (size_t)r * 8;
    float part = 0.f;
    #pragma unroll
    for (int w = 0; w < 8; ++w) {
        float4 e = e4[w], xv = x4[w];
        o4[w] = e;
        float a = e.x - xv.x; part += a * a;
        a = e.y - xv.y; part += a * a;
        a = e.z - xv.z; part += a * a;
        a = e.w - xv.w; part += a * a;
    }
    #pragma unroll
    for (int off = 32; off > 0; off >>= 1) part += __shfl_xor(part, off, 64);
    if ((threadIdx.x & 63) == 0) atomicAdd(mse, part);
}

// Pass 3: entropy over unused codes + total loss scalar.
__global__ __launch_bounds__(TPB) void vq_finish(
    const unsigned* __restrict__ minD, const unsigned* __restrict__ used,
    const float* __restrict__ mse, float* __restrict__ out, int n_elems)
{
    __shared__ float pp[4];
    const int tid = threadIdx.x;
    float s = 0.f;
    for (int k = tid; k < K_CODES; k += TPB)
        if (used[k] == 0u) s += __uint_as_float(minD[k]);
    #pragma unroll
    for (int off = 32; off > 0; off >>= 1) s += __shfl_xor(s, off, 64);
    const int lane = tid & 63, wid = tid >> 6;
    if (lane == 0) pp[wid] = s;
    __syncthreads();
    if (tid == 0) {
        float ent = (pp[0] + pp[1] + pp[2] + pp[3]) / (float)K_CODES;
        float m = mse[0] / (float)n_elems;
        out[n_elems] = 1.25f * m + 0.1f * ent;   // embedding+commitment+entropy
    }
}

extern "C" void kernel_launch(void* const* d_in, const int* in_sizes, int n_in,
                              void* d_out, int out_size, void* d_ws, size_t ws_size,
                              hipStream_t stream)
{
    (void)n_in; (void)out_size; (void)ws_size;
    const float* x  = (const float*)d_in[0];
    const float* cb = (const float*)d_in[1];
    float* out = (float*)d_out;
    const int n_elems = in_sizes[0];                 // 524288

    char* ws = (char*)d_ws;
    unsigned long long* rowBest = (unsigned long long*)(ws + WS_ROWBEST);
    unsigned* used = (unsigned*)(ws + WS_USED);
    unsigned* minD = (unsigned*)(ws + WS_MIND);
    float* mse = (float*)(ws + WS_MSE);
    float* xx  = (float*)(ws + WS_XX);
    float* nhc = (float*)(ws + WS_NHC);
    ushort* xhi = (ushort*)(ws + WS_XHI);
    ushort* xlo = (ushort*)(ws + WS_XLO);
    ushort* chi = (ushort*)(ws + WS_CHI);
    ushort* clo = (ushort*)(ws + WS_CLO);

    hipMemsetAsync(ws, 0, 163840, stream);                   // rowBest + used
    hipMemsetAsync(ws + WS_MIND, 0x7F, K_CODES * 4, stream); // +inf proxy
    hipMemsetAsync(ws + WS_MSE, 0, 4, stream);

    vq_prep<<<(N_ROWS + K_CODES) / TPB, TPB, 0, stream>>>(
        x, cb, xhi, xlo, chi, clo, xx, nhc);
    vq_dist<<<N_ROWS / 32, TPB, 0, stream>>>(
        xhi, xlo, chi, clo, xx, nhc, rowBest, minD);
    vq_emit<<<N_ROWS / TPB, TPB, 0, stream>>>(x, cb, rowBest, used, mse, out);
    vq_finish<<<1, TPB, 0, stream>>>(minD, used, mse, out, n_elems);
}

// Round 17
// 161.682 us; speedup vs baseline: 2.4143x; 1.3480x over previous
//
#include <hip/hip_runtime.h>

#define D 32
#define K_CODES 8192
#define N_ROWS 16384
#define TPB 256
#define BLKS_PER_RG 8              // code-split blocks per 32-row group
#define CPW 256                    // codes per wave (8192 / (8*4))
#define TILES (CPW / 16)           // 16 code-tiles per wave

typedef __attribute__((ext_vector_type(8))) short short8;   // 8 bf16 = 4 VGPR
typedef __attribute__((ext_vector_type(4))) float f32x4;    // MFMA C/D

// ws layout (bytes)
#define WS_ROWBEST 0               // u64 x 16384 = 131072
#define WS_USED    131072          // u32 x 8192
#define WS_MIND    163840          // u32 x 8192
#define WS_MSE     196608          // f32 (+pad)
#define WS_XX      196864          // f32 x 16384
#define WS_NHC     262400          // f32 x 8192
#define WS_XHI     295168          // bf16 x 16384*32 = 1 MB
#define WS_XLO     1343744         // 1 MB
#define WS_CHI     2392320         // bf16 x 8192*32 = 512 KB
#define WS_CLO     2916608         // 512 KB -> total 3440896 B

__device__ __forceinline__ unsigned sortkey(float f) {
    unsigned b = __float_as_uint(f);
    return b ^ ((unsigned)((int)b >> 31) | 0x80000000u);
}
// round-to-nearest-even fp32 -> bf16 (as ushort)
__device__ __forceinline__ unsigned rnbf16(float f) {
    unsigned u = __float_as_uint(f);
    return (u + 0x7FFFu + ((u >> 16) & 1u)) >> 16;
}
__device__ __forceinline__ float frombf16(unsigned h) {
    return __uint_as_float(h << 16);
}

// Pass 0: split rows+codes into hi/lo bf16; exact fp32 norms.
__global__ __launch_bounds__(TPB) void vq_prep(
    const float* __restrict__ x, const float* __restrict__ cb,
    ushort* __restrict__ xhi, ushort* __restrict__ xlo,
    ushort* __restrict__ chi, ushort* __restrict__ clo,
    float* __restrict__ xx, float* __restrict__ nhc)
{
    const int id = blockIdx.x * TPB + threadIdx.x;      // 0..24575
    const bool isrow = id < N_ROWS;
    const int e = isrow ? id : id - N_ROWS;
    const float4* src = (const float4*)(isrow ? x + (size_t)e * D
                                              : cb + (size_t)e * D);
    uint2* dhi = (uint2*)((isrow ? xhi : chi) + (size_t)e * D);
    uint2* dlo = (uint2*)((isrow ? xlo : clo) + (size_t)e * D);
    float ss = 0.f;
    #pragma unroll
    for (int w = 0; w < 8; ++w) {
        float4 v = src[w];
        ss += v.x*v.x + v.y*v.y + v.z*v.z + v.w*v.w;
        unsigned h0 = rnbf16(v.x), h1 = rnbf16(v.y);
        unsigned h2 = rnbf16(v.z), h3 = rnbf16(v.w);
        unsigned l0 = rnbf16(v.x - frombf16(h0)), l1 = rnbf16(v.y - frombf16(h1));
        unsigned l2 = rnbf16(v.z - frombf16(h2)), l3 = rnbf16(v.w - frombf16(h3));
        uint2 ph; ph.x = h0 | (h1 << 16); ph.y = h2 | (h3 << 16);
        uint2 pl; pl.x = l0 | (l1 << 16); pl.y = l2 | (l3 << 16);
        dhi[w] = ph; dlo[w] = pl;
    }
    if (isrow) xx[e] = ss; else nhc[e] = -0.5f * ss;
}

// argmax-only slot update (min-dist handled by tree below)
#define UPD(ACC, J, BS, BK)                                         \
    { float s_ = (ACC)[J];                                          \
      if (s_ > (BS)) { (BS) = s_; (BK) = kk; } }

// class-reduce packed best across the 16 cls lanes, publish one atomic
#define FLUSH(BS, BK, ROW)                                               \
    { unsigned kg = (unsigned)(kbase + (BK) * 16 + cls);                 \
      unsigned long long pk =                                            \
          ((unsigned long long)sortkey(BS) << 32) | (unsigned)(~kg);     \
      unsigned long long o_;                                             \
      o_ = __shfl_xor(pk, 1, 64); if (o_ > pk) pk = o_;                  \
      o_ = __shfl_xor(pk, 2, 64); if (o_ > pk) pk = o_;                  \
      o_ = __shfl_xor(pk, 4, 64); if (o_ > pk) pk = o_;                  \
      o_ = __shfl_xor(pk, 8, 64); if (o_ > pk) pk = o_;                  \
      if (cls == 0) atomicMax(&rowBest[ROW], pk); }

// Pass 1: split-bf16 MFMA distance sweep.
// Block = 32-row group x 1024-code slice; 4 waves x 256 codes (16 tiles).
// Grid 4096 = 16 blocks/CU -> full wave occupancy (was 512 blocks = 2/CU,
// latency-bound at 22% occupancy, r12). Work/traffic/atomics unchanged.
__global__ __launch_bounds__(TPB) void vq_dist(
    const ushort* __restrict__ xhi, const ushort* __restrict__ xlo,
    const ushort* __restrict__ chi, const ushort* __restrict__ clo,
    const float* __restrict__ xx, const float* __restrict__ nhc,
    unsigned long long* __restrict__ rowBest, unsigned* __restrict__ minD)
{
    const int tid  = threadIdx.x;
    const int lane = tid & 63;
    const int wid  = tid >> 6;                  // wave in block
    const int rg   = blockIdx.x >> 3;           // 0..511 row group
    const int bsp  = blockIdx.x & (BLKS_PER_RG - 1);
    const int r0   = rg * 32;
    const int kbase = (bsp * 4 + wid) * CPW;    // 32-way code split
    const int cls  = lane & 15;                 // A: row-in-tile / B: code-in-tile
    const int ks   = (lane >> 4) * 8;           // k-slot base (cancels A vs B)
    const int rs   = (lane >> 4) * 4;           // C/D row-slot base

    // A fragments: constant over the whole sweep (16 VGPR pinned).
    const short8 ah0 = *(const short8*)(xhi + (size_t)(r0 + cls) * D + ks);
    const short8 al0 = *(const short8*)(xlo + (size_t)(r0 + cls) * D + ks);
    const short8 ah1 = *(const short8*)(xhi + (size_t)(r0 + 16 + cls) * D + ks);
    const short8 al1 = *(const short8*)(xlo + (size_t)(r0 + 16 + cls) * D + ks);

    // Row norms for my 8 C/D slots.
    const float xx00 = xx[r0 + rs + 0], xx01 = xx[r0 + rs + 1];
    const float xx02 = xx[r0 + rs + 2], xx03 = xx[r0 + rs + 3];
    const float xx10 = xx[r0 + 16 + rs + 0], xx11 = xx[r0 + 16 + rs + 1];
    const float xx12 = xx[r0 + 16 + rs + 2], xx13 = xx[r0 + 16 + rs + 3];

    float bs00 = -3.0e38f, bs01 = -3.0e38f, bs02 = -3.0e38f, bs03 = -3.0e38f;
    float bs10 = -3.0e38f, bs11 = -3.0e38f, bs12 = -3.0e38f, bs13 = -3.0e38f;
    int bk00 = 0, bk01 = 0, bk02 = 0, bk03 = 0;
    int bk10 = 0, bk11 = 0, bk12 = 0, bk13 = 0;

    const ushort* bhp = chi + ((size_t)(kbase + cls) * D + ks);
    const ushort* blp = clo + ((size_t)(kbase + cls) * D + ks);
    const float*  nvp = nhc + kbase + cls;

    for (int kk = 0; kk < TILES; ++kk) {
        const short8 bh = *(const short8*)bhp;
        const short8 bl = *(const short8*)blp;
        const float  nv = *nvp;
        bhp += 16 * D; blp += 16 * D; nvp += 16;

        f32x4 acc0 = {nv, nv, nv, nv};    // scores pre-biased with -||c||^2/2
        f32x4 acc1 = acc0;
        acc0 = __builtin_amdgcn_mfma_f32_16x16x32_bf16(ah0, bh, acc0, 0, 0, 0);
        acc1 = __builtin_amdgcn_mfma_f32_16x16x32_bf16(ah1, bh, acc1, 0, 0, 0);
        acc0 = __builtin_amdgcn_mfma_f32_16x16x32_bf16(al0, bh, acc0, 0, 0, 0);
        acc1 = __builtin_amdgcn_mfma_f32_16x16x32_bf16(al1, bh, acc1, 0, 0, 0);
        acc0 = __builtin_amdgcn_mfma_f32_16x16x32_bf16(ah0, bl, acc0, 0, 0, 0);
        acc1 = __builtin_amdgcn_mfma_f32_16x16x32_bf16(ah1, bl, acc1, 0, 0, 0);
        acc0 = __builtin_amdgcn_mfma_f32_16x16x32_bf16(al0, bl, acc0, 0, 0, 0);
        acc1 = __builtin_amdgcn_mfma_f32_16x16x32_bf16(al1, bl, acc1, 0, 0, 0);

        // argmax updates (independent per slot)
        UPD(acc0, 0, bs00, bk00) UPD(acc0, 1, bs01, bk01)
        UPD(acc0, 2, bs02, bk02) UPD(acc0, 3, bs03, bk03)
        UPD(acc1, 0, bs10, bk10) UPD(acc1, 1, bs11, bk11)
        UPD(acc1, 2, bs12, bk12) UPD(acc1, 3, bs13, bk13)

        // min-dist over my 8 rows: depth-3 tree (fminf pairs fuse to v_min3)
        const float d0 = __builtin_fmaf(-2.f, acc0[0], xx00);
        const float d1 = __builtin_fmaf(-2.f, acc0[1], xx01);
        const float d2 = __builtin_fmaf(-2.f, acc0[2], xx02);
        const float d3 = __builtin_fmaf(-2.f, acc0[3], xx03);
        const float d4 = __builtin_fmaf(-2.f, acc1[0], xx10);
        const float d5 = __builtin_fmaf(-2.f, acc1[1], xx11);
        const float d6 = __builtin_fmaf(-2.f, acc1[2], xx12);
        const float d7 = __builtin_fmaf(-2.f, acc1[3], xx13);
        float md = fminf(fminf(fminf(d0, d1), fminf(d2, d3)),
                         fminf(fminf(d4, d5), fminf(d6, d7)));
        // fold the 4 row-groups holding this class column
        md = fminf(md, __shfl_xor(md, 16, 64));
        md = fminf(md, __shfl_xor(md, 32, 64));
        if (lane < 16)
            atomicMin(&minD[kbase + kk * 16 + cls], __float_as_uint(md));
    }

    FLUSH(bs00, bk00, r0 + rs + 0) FLUSH(bs01, bk01, r0 + rs + 1)
    FLUSH(bs02, bk02, r0 + rs + 2) FLUSH(bs03, bk03, r0 + rs + 3)
    FLUSH(bs10, bk10, r0 + 16 + rs + 0) FLUSH(bs11, bk11, r0 + 16 + rs + 1)
    FLUSH(bs12, bk12, r0 + 16 + rs + 2) FLUSH(bs13, bk13, r0 + 16 + rs + 3)
}

// Pass 2: finalize tokens -> gather emb, write out, fused MSE, mark used.
__global__ __launch_bounds__(TPB) void vq_emit(
    const float* __restrict__ x, const float* __restrict__ cb,
    const unsigned long long* __restrict__ rowBest,
    unsigned* __restrict__ used, float* __restrict__ mse,
    float* __restrict__ out)
{
    const int r = blockIdx.x * TPB + threadIdx.x;
    const unsigned tok = ~(unsigned)(rowBest[r] & 0xFFFFFFFFull);
    used[tok] = 1u;                        // benign race: all writers store 1
    const float4* e4 = (const float4*)cb + (size_t)tok * 8;
    const float4* x4 = (const float4*)x + (size_t)r * 8;
    float4* o4 = (float4*)out + (size_t)r * 8;
    float part = 0.f;
    #pragma unroll
    for (int w = 0; w < 8; ++w) {
        float4 e = e4[w], xv = x4[w];
        o4[w] = e;
        float a = e.x - xv.x; part += a * a;
        a = e.y - xv.y; part += a * a;
        a = e.z - xv.z; part += a * a;
        a = e.w - xv.w; part += a * a;
    }
    #pragma unroll
    for (int off = 32; off > 0; off >>= 1) part += __shfl_xor(part, off, 64);
    if ((threadIdx.x & 63) == 0) atomicAdd(mse, part);
}

// Pass 3: entropy over unused codes + total loss scalar.
__global__ __launch_bounds__(TPB) void vq_finish(
    const unsigned* __restrict__ minD, const unsigned* __restrict__ used,
    const float* __restrict__ mse, float* __restrict__ out, int n_elems)
{
    __shared__ float pp[4];
    const int tid = threadIdx.x;
    float s = 0.f;
    for (int k = tid; k < K_CODES; k += TPB)
        if (used[k] == 0u) s += __uint_as_float(minD[k]);
    #pragma unroll
    for (int off = 32; off > 0; off >>= 1) s += __shfl_xor(s, off, 64);
    const int lane = tid & 63, wid = tid >> 6;
    if (lane == 0) pp[wid] = s;
    __syncthreads();
    if (tid == 0) {
        float ent = (pp[0] + pp[1] + pp[2] + pp[3]) / (float)K_CODES;
        float m = mse[0] / (float)n_elems;
        out[n_elems] = 1.25f * m + 0.1f * ent;   // embedding+commitment+entropy
    }
}

extern "C" void kernel_launch(void* const* d_in, const int* in_sizes, int n_in,
                              void* d_out, int out_size, void* d_ws, size_t ws_size,
                              hipStream_t stream)
{
    (void)n_in; (void)out_size; (void)ws_size;
    const float* x  = (const float*)d_in[0];
    const float* cb = (const float*)d_in[1];
    float* out = (float*)d_out;
    const int n_elems = in_sizes[0];                 // 524288

    char* ws = (char*)d_ws;
    unsigned long long* rowBest = (unsigned long long*)(ws + WS_ROWBEST);
    unsigned* used = (unsigned*)(ws + WS_USED);
    unsigned* minD = (unsigned*)(ws + WS_MIND);
    float* mse = (float*)(ws + WS_MSE);
    float* xx  = (float*)(ws + WS_XX);
    float* nhc = (float*)(ws + WS_NHC);
    ushort* xhi = (ushort*)(ws + WS_XHI);
    ushort* xlo = (ushort*)(ws + WS_XLO);
    ushort* chi = (ushort*)(ws + WS_CHI);
    ushort* clo = (ushort*)(ws + WS_CLO);

    hipMemsetAsync(ws, 0, 163840, stream);                   // rowBest + used
    hipMemsetAsync(ws + WS_MIND, 0x7F, K_CODES * 4, stream); // +inf proxy
    hipMemsetAsync(ws + WS_MSE, 0, 4, stream);

    vq_prep<<<(N_ROWS + K_CODES) / TPB, TPB, 0, stream>>>(
        x, cb, xhi, xlo, chi, clo, xx, nhc);
    vq_dist<<<(N_ROWS / 32) * BLKS_PER_RG, TPB, 0, stream>>>(
        xhi, xlo, chi, clo, xx, nhc, rowBest, minD);
    vq_emit<<<N_ROWS / TPB, TPB, 0, stream>>>(x, cb, rowBest, used, mse, out);
    vq_finish<<<1, TPB, 0, stream>>>(minD, used, mse, out, n_elems);
}